// Round 9
// baseline (505.554 us; speedup 1.0000x reference)
//
#include <hip/hip_runtime.h>
#include <hip/hip_bf16.h>
#include <stdint.h>

#define T_SEQ  2048
#define HIDDEN 4096
#define NHEAD  32
#define NKV    8
#define HDIM   128
#define NQKV   6144      // (32 + 2*8) * 128
#define WINDOW 1024
#define SCALE  0.08838834764831845f   // 1/sqrt(128)
// |score| <= ||q||*||k||*SCALE = 128/sqrt(128) = 11.32 (RMSNorm, w=1) -> fixed shift
#define SHIFT  12.0f

typedef __attribute__((ext_vector_type(8))) short          short8;    // 8 bf16
typedef __attribute__((ext_vector_type(8))) unsigned short ushort8_t;
typedef __attribute__((ext_vector_type(4))) float          floatx4;

__device__ __forceinline__ unsigned short f2bf(float f) {
    union { float f; unsigned int u; } v; v.f = f;
    unsigned int u = v.u;
    unsigned int r = (u + 0x7FFFu + ((u >> 16) & 1u)) >> 16;  // RNE
    return (unsigned short)r;
}
__device__ __forceinline__ float bf2f(unsigned short u) {
    union { unsigned int u; float f; } v; v.u = ((unsigned int)u) << 16;
    return v.f;
}

#define GLOBAL_AS(p) ((const __attribute__((address_space(1))) void*)(p))
#define LDS_AS(p)    ((__attribute__((address_space(3))) void*)(p))

// raw barrier: no implicit vmcnt/lgkm drain. asm memory clobbers stop the
// compiler moving LDS/global ops across it.
#define S_BARRIER() do { asm volatile("" ::: "memory");  \
                         __builtin_amdgcn_s_barrier();   \
                         asm volatile("" ::: "memory"); } while (0)

// ---------------------------------------------------------------- convert fp32 -> bf16
__global__ __launch_bounds__(256) void convert_bf16_kernel(
        const float* __restrict__ X, unsigned short* __restrict__ Y, int n4) {
    int i = blockIdx.x * blockDim.x + threadIdx.x;
    if (i < n4) {
        float4 v = ((const float4*)X)[i];
        ushort4 o;
        o.x = f2bf(v.x); o.y = f2bf(v.y); o.z = f2bf(v.z); o.w = f2bf(v.w);
        ((ushort4*)Y)[i] = o;
    }
}

// ------------------- transpose K x N fp32 -> N x K bf16 (tile 32n x 128k, vectorized)
__global__ __launch_bounds__(256) void transpose_bf16_kernel(
        const float* __restrict__ W, unsigned short* __restrict__ Wt, int K, int N) {
    __shared__ float tile[128][33];
    const int n0 = blockIdx.x * 32, k0 = blockIdx.y * 128;
    const int tid = threadIdx.x;
    const int rr = tid >> 3, cc = tid & 7;        // read: 32 rows/pass, 8 float4 cols
    #pragma unroll
    for (int p = 0; p < 4; ++p) {
        int r = p * 32 + rr;
        float4 v = *(const float4*)&W[(size_t)(k0 + r) * N + n0 + cc * 4];
        tile[r][cc * 4 + 0] = v.x; tile[r][cc * 4 + 1] = v.y;
        tile[r][cc * 4 + 2] = v.z; tile[r][cc * 4 + 3] = v.w;
    }
    __syncthreads();
    const int nL = tid >> 3, kc = tid & 7;        // write: 32 n rows, 8 k-chunks
    #pragma unroll
    for (int q = 0; q < 2; ++q) {
        int kbase = kc * 8 + q * 64;
        ushort8_t o;
        #pragma unroll
        for (int j = 0; j < 8; ++j) o[j] = f2bf(tile[kbase + j][nL]);
        *(ushort8_t*)&Wt[(size_t)(n0 + nL) * K + k0 + kbase] = o;
    }
}

// ---------------------------------------------------------------- bf16 MFMA GEMM
// gemm_bt3: 128x128 tile, BK=64, 256 threads (2x2 waves, wave tile 64x64),
// 2-buffer ring, 64 KiB LDS -> 2 blocks/CU. ~1000 TF on a tail-free 512-block
// grid (GEMM2). One vmcnt(0)+barrier per 64-K step; next tile's global_load_lds
// issued before this tile's compute. XOR swizzle (slot^=row&7) both sides;
// 0 bank conflicts measured.
#define STG3_A(bufi, kt, r)                                                       \
    __builtin_amdgcn_global_load_lds(                                             \
        GLOBAL_AS(A + (size_t)(m0 + rRow[r]) * K + ((kt) << 6) + rOff[r]),        \
        LDS_AS(&As3[bufi][((r) * 256 + tid) * 8]), 16, 0, 0)
#define STG3_B(bufi, kt, r)                                                       \
    __builtin_amdgcn_global_load_lds(                                             \
        GLOBAL_AS(B + (size_t)(n0 + rRow[r]) * K + ((kt) << 6) + rOff[r]),        \
        LDS_AS(&Bs3[bufi][((r) * 256 + tid) * 8]), 16, 0, 0)

template <bool BF16_OUT>
__global__ __launch_bounds__(256, 2) void gemm_bt3_kernel(
        const unsigned short* __restrict__ A,
        const unsigned short* __restrict__ B,
        void* __restrict__ Cv, int M, int N, int K) {
    __shared__ __align__(16) unsigned short As3[2][128 * 64];   // 32 KiB
    __shared__ __align__(16) unsigned short Bs3[2][128 * 64];   // 32 KiB

    const int tid  = threadIdx.x;
    const int lane = tid & 63, wave = tid >> 6;
    const int wr = wave >> 1, wc = wave & 1;       // 2x2 wave grid, wave tile 64x64
    const int lrow = lane & 15, hi = lane >> 4;

    // XCD-aware bijective swizzle (both grids are multiples of 8)
    const int nwg = gridDim.x * gridDim.y;
    int wg = blockIdx.y * gridDim.x + blockIdx.x;
    wg = (wg & 7) * (nwg >> 3) + (wg >> 3);
    const int bx = wg % gridDim.x;
    const int by = wg / gridDim.x;
    const int m0 = by * 128, n0 = bx * 128;

    const int NT = K >> 6;

    // staging map: LDS linear (global_load_lds), source k pre-swizzled so logical
    // slot s of row r lives at physical slot (s ^ (r&7)). 8 lanes x 16B per row.
    int rRow[4], rOff[4];
    #pragma unroll
    for (int r = 0; r < 4; ++r) {
        int idx = r * 256 + tid;
        int row = idx >> 3;
        rRow[r] = row;
        rOff[r] = ((idx & 7) ^ (row & 7)) * 8;
    }

    // frag-read offsets (ushort units): row*64 + (slot ^ (row&7))*8
    const int sA0   = (hi ^ (lrow & 7)) * 8;       // kh toggles via ^32
    const int aBase = (wr * 64 + lrow) * 64;
    const int bBase = (wc * 64 + lrow) * 64;

    floatx4 acc[4][4] = {};

    auto compute_tile = [&](int cur) {
        const unsigned short* ap = &As3[cur][0];
        const unsigned short* bp = &Bs3[cur][0];
        short8 af[4][2], bf[4][2];
        #pragma unroll
        for (int m = 0; m < 4; ++m)
            #pragma unroll
            for (int kh = 0; kh < 2; ++kh)
                af[m][kh] = *(const short8*)(ap + aBase + m * 1024 + (sA0 ^ (kh << 5)));
        #pragma unroll
        for (int n = 0; n < 4; ++n)
            #pragma unroll
            for (int kh = 0; kh < 2; ++kh)
                bf[n][kh] = *(const short8*)(bp + bBase + n * 1024 + (sA0 ^ (kh << 5)));
        __builtin_amdgcn_s_setprio(1);
        #pragma unroll
        for (int m = 0; m < 4; ++m)
            #pragma unroll
            for (int n = 0; n < 4; ++n) {
                acc[m][n] = __builtin_amdgcn_mfma_f32_16x16x32_bf16(
                    af[m][0], bf[n][0], acc[m][n], 0, 0, 0);
                acc[m][n] = __builtin_amdgcn_mfma_f32_16x16x32_bf16(
                    af[m][1], bf[n][1], acc[m][n], 0, 0, 0);
            }
        __builtin_amdgcn_s_setprio(0);
    };

    // prologue: stage tile 0 into buf 0
    #pragma unroll
    for (int r = 0; r < 4; ++r) STG3_A(0, 0, r);
    #pragma unroll
    for (int r = 0; r < 4; ++r) STG3_B(0, 0, r);
    asm volatile("s_waitcnt vmcnt(0)" ::: "memory");
    S_BARRIER();

    for (int t = 0; t < NT - 1; ++t) {
        const int cur = t & 1;
        // issue next tile's loads first: latency hides under this tile's compute
        #pragma unroll
        for (int r = 0; r < 4; ++r) STG3_A(cur ^ 1, t + 1, r);
        #pragma unroll
        for (int r = 0; r < 4; ++r) STG3_B(cur ^ 1, t + 1, r);
        compute_tile(cur);
        asm volatile("s_waitcnt vmcnt(0)" ::: "memory");
        S_BARRIER();
    }
    compute_tile((NT - 1) & 1);

    const int rowb = hi * 4, col = lrow;
    #pragma unroll
    for (int mi = 0; mi < 4; ++mi)
        #pragma unroll
        for (int ni = 0; ni < 4; ++ni) {
            size_t base = (size_t)(m0 + wr * 64 + mi * 16 + rowb) * N
                        + (n0 + wc * 64 + ni * 16 + col);
            #pragma unroll
            for (int r = 0; r < 4; ++r) {
                if (BF16_OUT)
                    ((unsigned short*)Cv)[base + (size_t)r * N] = f2bf(acc[mi][ni][r]);
                else
                    ((float*)Cv)[base + (size_t)r * N] = acc[mi][ni][r];
            }
        }
}

// gemm_bt4: 128x192 tile for GEMM1 (M=2048, N=6144): grid 16x32 = 512 blocks =
// exactly 2 blocks/CU in ONE dispatch round. Measured R6: 111.8 µs (922 TF),
// MfmaUtil 39.6%, FETCH 92 MB, 0 bank conflicts. Same bt3 schedule/swizzle;
// 2x2 waves, per-wave 64x96; LDS 80 KiB -> 2 blocks/CU; M-fastest tile order
// within each XCD chunk.
#define STG4_A(bufi, kt, r)                                                       \
    __builtin_amdgcn_global_load_lds(                                             \
        GLOBAL_AS(A + (size_t)(m0 + rRowA[r]) * K + ((kt) << 6) + rOffA[r]),      \
        LDS_AS(&As4[bufi][((r) * 256 + tid) * 8]), 16, 0, 0)
#define STG4_B(bufi, kt, r)                                                       \
    __builtin_amdgcn_global_load_lds(                                             \
        GLOBAL_AS(B + (size_t)(n0 + rRowB[r]) * K + ((kt) << 6) + rOffB[r]),      \
        LDS_AS(&Bs4[bufi][((r) * 256 + tid) * 8]), 16, 0, 0)

template <bool BF16_OUT>
__global__ __launch_bounds__(256, 2) void gemm_bt4_kernel(
        const unsigned short* __restrict__ A,
        const unsigned short* __restrict__ B,
        void* __restrict__ Cv, int M, int N, int K) {
    __shared__ __align__(16) unsigned short As4[2][128 * 64];   // 32 KiB
    __shared__ __align__(16) unsigned short Bs4[2][192 * 64];   // 48 KiB

    const int tid  = threadIdx.x;
    const int lane = tid & 63, wave = tid >> 6;
    const int wr = wave >> 1, wc = wave & 1;       // 2x2 wave grid, wave tile 64x96
    const int lrow = lane & 15, hi = lane >> 4;

    // XCD remap, then M-fastest tile order (gridDim.x = M-tiles)
    const int nwg = gridDim.x * gridDim.y;
    int wg = blockIdx.y * gridDim.x + blockIdx.x;
    wg = (wg & 7) * (nwg >> 3) + (wg >> 3);
    const int by = wg % gridDim.x;        // M-tile (fastest within XCD chunk)
    const int bx = wg / gridDim.x;        // N-tile
    const int m0 = by * 128, n0 = bx * 192;

    const int NT = K >> 6;

    // staging maps (source pre-swizzled: logical slot s of row r -> s ^ (r&7))
    int rRowA[4], rOffA[4];
    #pragma unroll
    for (int r = 0; r < 4; ++r) {
        int idx = r * 256 + tid;
        int row = idx >> 3;
        rRowA[r] = row;
        rOffA[r] = ((idx & 7) ^ (row & 7)) * 8;
    }
    int rRowB[6], rOffB[6];
    #pragma unroll
    for (int r = 0; r < 6; ++r) {
        int idx = r * 256 + tid;
        int row = idx >> 3;
        rRowB[r] = row;
        rOffB[r] = ((idx & 7) ^ (row & 7)) * 8;
    }

    const int sA0   = (hi ^ (lrow & 7)) * 8;       // kh toggles via ^32
    const int aBase = (wr * 64 + lrow) * 64;
    const int bBase = (wc * 96 + lrow) * 64;

    floatx4 acc[4][6] = {};

    auto compute_tile = [&](int cur) {
        const unsigned short* ap = &As4[cur][0];
        const unsigned short* bp = &Bs4[cur][0];
        short8 af[4][2], bf[6][2];
        #pragma unroll
        for (int m = 0; m < 4; ++m)
            #pragma unroll
            for (int kh = 0; kh < 2; ++kh)
                af[m][kh] = *(const short8*)(ap + aBase + m * 1024 + (sA0 ^ (kh << 5)));
        #pragma unroll
        for (int n = 0; n < 6; ++n)
            #pragma unroll
            for (int kh = 0; kh < 2; ++kh)
                bf[n][kh] = *(const short8*)(bp + bBase + n * 1024 + (sA0 ^ (kh << 5)));
        __builtin_amdgcn_s_setprio(1);
        #pragma unroll
        for (int m = 0; m < 4; ++m)
            #pragma unroll
            for (int n = 0; n < 6; ++n) {
                acc[m][n] = __builtin_amdgcn_mfma_f32_16x16x32_bf16(
                    af[m][0], bf[n][0], acc[m][n], 0, 0, 0);
                acc[m][n] = __builtin_amdgcn_mfma_f32_16x16x32_bf16(
                    af[m][1], bf[n][1], acc[m][n], 0, 0, 0);
            }
        __builtin_amdgcn_s_setprio(0);
    };

    // prologue: stage tile 0 into buf 0
    #pragma unroll
    for (int r = 0; r < 4; ++r) STG4_A(0, 0, r);
    #pragma unroll
    for (int r = 0; r < 6; ++r) STG4_B(0, 0, r);
    asm volatile("s_waitcnt vmcnt(0)" ::: "memory");
    S_BARRIER();

    for (int t = 0; t < NT - 1; ++t) {
        const int cur = t & 1;
        #pragma unroll
        for (int r = 0; r < 4; ++r) STG4_A(cur ^ 1, t + 1, r);
        #pragma unroll
        for (int r = 0; r < 6; ++r) STG4_B(cur ^ 1, t + 1, r);
        compute_tile(cur);
        asm volatile("s_waitcnt vmcnt(0)" ::: "memory");
        S_BARRIER();
    }
    compute_tile((NT - 1) & 1);

    const int rowb = hi * 4, col = lrow;
    #pragma unroll
    for (int mi = 0; mi < 4; ++mi)
        #pragma unroll
        for (int ni = 0; ni < 6; ++ni) {
            size_t base = (size_t)(m0 + wr * 64 + mi * 16 + rowb) * N
                        + (n0 + wc * 96 + ni * 16 + col);
            #pragma unroll
            for (int r = 0; r < 4; ++r) {
                if (BF16_OUT)
                    ((unsigned short*)Cv)[base + (size_t)r * N] = f2bf(acc[mi][ni][r]);
                else
                    ((float*)Cv)[base + (size_t)r * N] = acc[mi][ni][r];
            }
        }
}

// ------------------------------------- rope table: [t][i] -> (cos, sin), i in [0,64)
__global__ __launch_bounds__(256) void rope_table_kernel(
        const int* __restrict__ positions, float2* __restrict__ rope) {
    int idx = blockIdx.x * 256 + threadIdx.x;   // t*64 + i
    int t = idx >> 6, i = idx & 63;
    float inv_freq = expf((float)i * -0.2158673524681918f);   // -ln(1e6)/64
    float sn, cs;
    sincosf((float)positions[t] * inv_freq, &sn, &cs);
    rope[idx] = make_float2(cs, sn);
}

// ------------------------- qkv post: RMSNorm+RoPE (q,k) + V transpose, bf16 -> bf16
// grid (T/32, 48): heads 0-31 q, 32-39 k, 40-47 v. Block 256.
__global__ __launch_bounds__(256) void qkv_post_kernel(
        const unsigned short* __restrict__ qkv, const float2* __restrict__ rope,
        const float* __restrict__ qw, const float* __restrict__ kw,
        unsigned short* __restrict__ qb,        // [T][32][128]
        unsigned short* __restrict__ kb,        // [T][8][128]
        unsigned short* __restrict__ vbT) {     // [8][128][T]
    const int head = blockIdx.y;
    const int t0   = blockIdx.x * 32;
    const int tid  = threadIdx.x;

    if (head < 40) {
        const int r  = tid >> 3;       // token row 0..31
        const int q8 = tid & 7;        // 8 threads/row, 16 elems each
        const int t  = t0 + r;
        const unsigned short* src = qkv + (size_t)t * NQKV
                         + (head < 32 ? head * 128 : 4096 + (head - 32) * 128)
                         + q8 * 16;
        const float* w = (head < 32) ? qw : kw;

        ushort8_t u0 = *(const ushort8_t*)src;
        ushort8_t u1 = *(const ushort8_t*)(src + 8);
        float x[16];
        #pragma unroll
        for (int j = 0; j < 8; ++j) { x[j] = bf2f(u0[j]); x[8 + j] = bf2f(u1[j]); }

        float ss = 0.f;
        #pragma unroll
        for (int j = 0; j < 16; ++j) ss = fmaf(x[j], x[j], ss);
        ss += __shfl_xor(ss, 1); ss += __shfl_xor(ss, 2); ss += __shfl_xor(ss, 4);
        float sc = rsqrtf(ss * (1.f / 128.f) + 1e-5f);

        float xn[16], xp[16];
        #pragma unroll
        for (int j = 0; j < 16; ++j) xn[j] = x[j] * sc * w[q8 * 16 + j];
        #pragma unroll
        for (int j = 0; j < 16; ++j) xp[j] = __shfl_xor(xn[j], 4);

        const float2* rp = rope + (size_t)t * 64 + (q8 & 3) * 16;
        ushort8_t o0, o1;
        #pragma unroll
        for (int j = 0; j < 8; ++j) {
            float2 cs = rp[j];
            float res = (q8 < 4) ? (xn[j] * cs.x - xp[j] * cs.y)
                                 : (xn[j] * cs.x + xp[j] * cs.y);
            o0[j] = f2bf(res);
        }
        #pragma unroll
        for (int j = 0; j < 8; ++j) {
            float2 cs = rp[8 + j];
            float res = (q8 < 4) ? (xn[8+j] * cs.x - xp[8+j] * cs.y)
                                 : (xn[8+j] * cs.x + xp[8+j] * cs.y);
            o1[j] = f2bf(res);
        }
        unsigned short* dst = (head < 32)
            ? qb + ((size_t)t * 32 + head) * 128 + q8 * 16
            : kb + ((size_t)t * 8 + (head - 32)) * 128 + q8 * 16;
        *(ushort8_t*)dst       = o0;
        *(ushort8_t*)(dst + 8) = o1;
    } else {
        __shared__ float tile[128][33];
        const int hk = head - 40;
        {
            const int r = tid >> 3, c8 = tid & 7;
            const unsigned short* src =
                qkv + (size_t)(t0 + r) * NQKV + 5120 + hk * 128 + c8 * 16;
            ushort8_t u0 = *(const ushort8_t*)src;
            ushort8_t u1 = *(const ushort8_t*)(src + 8);
            #pragma unroll
            for (int j = 0; j < 8; ++j) {
                tile[c8 * 16 + j][r]     = bf2f(u0[j]);
                tile[c8 * 16 + 8 + j][r] = bf2f(u1[j]);
            }
        }
        __syncthreads();
        {
            const int d = tid >> 1, th = tid & 1;
            ushort8_t o0, o1;
            #pragma unroll
            for (int j = 0; j < 8; ++j) o0[j] = f2bf(tile[d][th * 16 + j]);
            #pragma unroll
            for (int j = 0; j < 8; ++j) o1[j] = f2bf(tile[d][th * 16 + 8 + j]);
            unsigned short* dst = vbT + ((size_t)hk * 128 + d) * T_SEQ + t0 + th * 16;
            *(ushort8_t*)dst       = o0;
            *(ushort8_t*)(dst + 8) = o1;
        }
    }
}

// ------------------- MFMA sliding-window flash attention, fixed-shift softmax
// p = exp(score - SHIFT) is safe: |score| <= 11.32 provably (see SHIFT above).
// No running max / rescale; l accumulated per-lane, reduced once in epilogue.
// v2: double-buffered K/V staging (bt3 pattern) — issue tile t+1's
// global_load_lds before computing tile t, one vmcnt(0)+barrier per tile.
// Race-free by the bt3 argument: all reads of the target buffer completed
// before the previous barrier (lgkmcnt drained before each wave's MFMAs).
// LDS 37.9 KB -> still 4 blocks/CU.
__global__ __launch_bounds__(256) void attention_kernel(
        const unsigned short* __restrict__ qb,
        const unsigned short* __restrict__ kb,
        const unsigned short* __restrict__ vbT,
        unsigned short* __restrict__ attnb) {
    const int h    = blockIdx.x & 31;
    const int Q0   = (blockIdx.x >> 5) * 64;
    const int tid  = threadIdx.x, wave = tid >> 6, lane = tid & 63;
    const int keyA = lane & 15, g = lane >> 4;
    const int hk   = h >> 2;
    const int qlo  = Q0 + wave * 16;

    __shared__ __align__(16) unsigned short ks [2][32 * 128];   // [key][d]
    __shared__ __align__(16) unsigned short vsT[2][128 * 32];   // [d][key]
    __shared__ __align__(16) unsigned short Pa [4 * 16 * 40];   // per-wave 16x32 (+8 pad)

    unsigned short* pw = Pa + wave * 640;

    // per-thread staging addresses (c = i*256+tid for i in {0,1})
    int kRow[2], kOff[2], vD[2], vOff[2];
    #pragma unroll
    for (int i = 0; i < 2; ++i) {
        int c = i * 256 + tid;
        {   int row = c >> 4, u = c & 15;
            kRow[i] = row; kOff[i] = (u ^ (row & 7)) * 8; }
        {   int d = c >> 2, u = c & 3;
            vD[i] = d; vOff[i] = (u ^ (d & 3)) * 8; }
    }

    auto stage = [&](int buf, int s0) {
        #pragma unroll
        for (int i = 0; i < 2; ++i) {
            int c = i * 256 + tid;
            const unsigned short* kp =
                kb + ((size_t)(s0 + kRow[i]) * 8 + hk) * 128 + kOff[i];
            __builtin_amdgcn_global_load_lds(GLOBAL_AS(kp),
                LDS_AS(&ks[buf][c * 8]), 16, 0, 0);
            const unsigned short* vp =
                vbT + ((size_t)hk * 128 + vD[i]) * T_SEQ + s0 + vOff[i];
            __builtin_amdgcn_global_load_lds(GLOBAL_AS(vp),
                LDS_AS(&vsT[buf][c * 8]), 16, 0, 0);
        }
    };

    short8 qa[4];
    {
        const unsigned short* qp = qb + ((size_t)(qlo + keyA) * 32 + h) * 128 + g * 8;
        #pragma unroll
        for (int s = 0; s < 4; ++s) qa[s] = *(const short8*)(qp + s * 32);
    }

    floatx4 acc[8] = {};
    float l_part[4] = {0.f, 0.f, 0.f, 0.f};

    const int s_begin = (Q0 >= WINDOW) ? ((Q0 - (WINDOW - 1)) & ~31) : 0;
    const int s_end   = Q0 + 63;

    // prologue: stage first tile
    stage(0, s_begin);
    asm volatile("s_waitcnt vmcnt(0)" ::: "memory");
    S_BARRIER();

    int cur = 0;
    for (int s0 = s_begin; s0 <= s_end; s0 += 32) {
        if (s0 + 32 <= s_end) stage(cur ^ 1, s0 + 32);   // prefetch next tile

        if (s0 <= qlo + 15 && s0 + 31 >= qlo - (WINDOW - 1)) {
            const unsigned short* ksb  = &ks[cur][0];
            const unsigned short* vsb  = &vsT[cur][0];
            floatx4 sa0 = {}, sa1 = {};
            #pragma unroll
            for (int kst = 0; kst < 4; ++kst) {
                int u = g + 4 * kst;
                short8 k0 = *(const short8*)(ksb + keyA * 128 + (u ^ (keyA & 7)) * 8);
                short8 k1 = *(const short8*)(ksb + (16 + keyA) * 128 + (u ^ ((16 + keyA) & 7)) * 8);
                sa0 = __builtin_amdgcn_mfma_f32_16x16x32_bf16(qa[kst], k0, sa0, 0, 0, 0);
                sa1 = __builtin_amdgcn_mfma_f32_16x16x32_bf16(qa[kst], k1, sa1, 0, 0, 0);
            }
            float p0[4], p1[4];
            #pragma unroll
            for (int r = 0; r < 4; ++r) {
                int row = qlo + 4 * g + r;
                int sA = s0 + keyA, sB = sA + 16;
                bool vA = (sA <= row) && (row - sA < WINDOW);
                bool vB = (sB <= row) && (row - sB < WINDOW);
                p0[r] = vA ? __expf(fmaf(sa0[r], SCALE, -SHIFT)) : 0.f;
                p1[r] = vB ? __expf(fmaf(sa1[r], SCALE, -SHIFT)) : 0.f;
                l_part[r] += p0[r] + p1[r];
            }
            #pragma unroll
            for (int r = 0; r < 4; ++r) {
                pw[(4 * g + r) * 40 + keyA]      = f2bf(p0[r]);
                pw[(4 * g + r) * 40 + keyA + 16] = f2bf(p1[r]);
            }
            short8 pf = *(const short8*)(pw + keyA * 40 + g * 8);

            #pragma unroll
            for (int t = 0; t < 8; ++t) {
                int d = t * 16 + keyA;
                short8 vf = *(const short8*)(vsb + d * 32 + (g ^ (d & 3)) * 8);
                acc[t] = __builtin_amdgcn_mfma_f32_16x16x32_bf16(pf, vf, acc[t], 0, 0, 0);
            }
        }
        asm volatile("s_waitcnt vmcnt(0)" ::: "memory");
        S_BARRIER();
        cur ^= 1;
    }

    float inv[4];
    #pragma unroll
    for (int r = 0; r < 4; ++r) {
        float l = l_part[r];
        l += __shfl_xor(l, 1); l += __shfl_xor(l, 2);
        l += __shfl_xor(l, 4); l += __shfl_xor(l, 8);
        inv[r] = 1.f / l;
    }
    #pragma unroll
    for (int t = 0; t < 8; ++t)
        #pragma unroll
        for (int r = 0; r < 4; ++r)
            attnb[(size_t)(qlo + 4 * g + r) * 4096 + h * 128 + t * 16 + keyA] =
                f2bf(acc[t][r] * inv[r]);
}

// ----------------------------------------------------------------------- launcher
extern "C" void kernel_launch(void* const* d_in, const int* in_sizes, int n_in,
                              void* d_out, int out_size, void* d_ws, size_t ws_size,
                              hipStream_t stream) {
    const int*   positions = (const int*)  d_in[0];
    const float* hs        = (const float*)d_in[1];
    const float* w_qkv     = (const float*)d_in[2];
    const float* q_norm_w  = (const float*)d_in[3];
    const float* k_norm_w  = (const float*)d_in[4];
    const float* w_o       = (const float*)d_in[5];
    float* out = (float*)d_out;

    char* ws = (char*)d_ws;
    // layout (121 MB):
    //   [0,16M)    hs bf16     (dead after gemm1; reused as attnb bf16)
    //   [16M,64M)  w_qkv^T bf16 (dead after gemm1; then qb/kb/vbT/rope live here)
    //     [16M,32M) qb bf16 [T][32][128]
    //     [32M,36M) kb bf16 [T][8][128]
    //     [36M,40M) vbT bf16 [8][128][T]
    //     [40M,41M) rope float2 [T][64]
    //   [64M,96M)  w_o^T bf16
    //   [96M,120M) qkv bf16 [T][6144]
    unsigned short* hsb   = (unsigned short*)(ws);
    unsigned short* wqkvt = (unsigned short*)(ws + (size_t)(16u << 20));
    unsigned short* wot   = (unsigned short*)(ws + (size_t)(64u << 20));
    unsigned short* qkvb  = (unsigned short*)(ws + (size_t)(96u << 20));
    unsigned short* qb    = (unsigned short*)(ws + (size_t)(16u << 20));
    unsigned short* kb    = (unsigned short*)(ws + (size_t)(32u << 20));
    unsigned short* vbT   = (unsigned short*)(ws + (size_t)(36u << 20));
    float2*         rope  = (float2*)        (ws + (size_t)(40u << 20));
    unsigned short* attnb = hsb;   // alias: hs-bf16 dead after gemm1

    convert_bf16_kernel<<<dim3((T_SEQ * HIDDEN / 4 + 255) / 256), 256, 0, stream>>>(
        hs, hsb, T_SEQ * HIDDEN / 4);
    transpose_bf16_kernel<<<dim3(NQKV / 32, HIDDEN / 128), 256, 0, stream>>>(
        w_qkv, wqkvt, HIDDEN, NQKV);
    transpose_bf16_kernel<<<dim3(HIDDEN / 32, HIDDEN / 128), 256, 0, stream>>>(
        w_o, wot, HIDDEN, HIDDEN);
    gemm_bt4_kernel<true><<<dim3(T_SEQ / 128, NQKV / 192), 256, 0, stream>>>(
        hsb, wqkvt, qkvb, T_SEQ, NQKV, HIDDEN);
    rope_table_kernel<<<dim3(T_SEQ * 64 / 256), 256, 0, stream>>>(positions, rope);
    qkv_post_kernel<<<dim3(T_SEQ / 32, 48), 256, 0, stream>>>(
        qkvb, rope, q_norm_w, k_norm_w, qb, kb, vbT);
    attention_kernel<<<dim3((T_SEQ / 64) * NHEAD), 256, 0, stream>>>(
        qb, kb, vbT, attnb);
    gemm_bt3_kernel<false><<<dim3(HIDDEN / 128, T_SEQ / 128), 256, 0, stream>>>(
        attnb, wot, out, T_SEQ, HIDDEN, HIDDEN);
}

// Round 11
// 488.066 us; speedup vs baseline: 1.0358x; 1.0358x over previous
//
#include <hip/hip_runtime.h>
#include <hip/hip_bf16.h>
#include <stdint.h>

#define T_SEQ  2048
#define HIDDEN 4096
#define NHEAD  32
#define NKV    8
#define HDIM   128
#define NQKV   6144      // (32 + 2*8) * 128
#define WINDOW 1024
#define SCALE  0.08838834764831845f   // 1/sqrt(128)
// |score| <= ||q||*||k||*SCALE = 128/sqrt(128) = 11.32 (RMSNorm, w=1) -> fixed shift
#define SHIFT  12.0f

typedef __attribute__((ext_vector_type(8))) short          short8;    // 8 bf16
typedef __attribute__((ext_vector_type(8))) unsigned short ushort8_t;
typedef __attribute__((ext_vector_type(4))) float          floatx4;

__device__ __forceinline__ unsigned short f2bf(float f) {
    union { float f; unsigned int u; } v; v.f = f;
    unsigned int u = v.u;
    unsigned int r = (u + 0x7FFFu + ((u >> 16) & 1u)) >> 16;  // RNE
    return (unsigned short)r;
}
__device__ __forceinline__ float bf2f(unsigned short u) {
    union { unsigned int u; float f; } v; v.u = ((unsigned int)u) << 16;
    return v.f;
}

#define GLOBAL_AS(p) ((const __attribute__((address_space(1))) void*)(p))
#define LDS_AS(p)    ((__attribute__((address_space(3))) void*)(p))

// raw barrier: no implicit vmcnt/lgkm drain. asm memory clobbers stop the
// compiler moving LDS/global ops across it.
#define S_BARRIER() do { asm volatile("" ::: "memory");  \
                         __builtin_amdgcn_s_barrier();   \
                         asm volatile("" ::: "memory"); } while (0)

// ---------------------------------------------------------------- convert fp32 -> bf16
__global__ __launch_bounds__(256) void convert_bf16_kernel(
        const float* __restrict__ X, unsigned short* __restrict__ Y, int n4) {
    int i = blockIdx.x * blockDim.x + threadIdx.x;
    if (i < n4) {
        float4 v = ((const float4*)X)[i];
        ushort4 o;
        o.x = f2bf(v.x); o.y = f2bf(v.y); o.z = f2bf(v.z); o.w = f2bf(v.w);
        ((ushort4*)Y)[i] = o;
    }
}

// ------------------- transpose K x N fp32 -> N x K bf16 (tile 32n x 128k, vectorized)
__global__ __launch_bounds__(256) void transpose_bf16_kernel(
        const float* __restrict__ W, unsigned short* __restrict__ Wt, int K, int N) {
    __shared__ float tile[128][33];
    const int n0 = blockIdx.x * 32, k0 = blockIdx.y * 128;
    const int tid = threadIdx.x;
    const int rr = tid >> 3, cc = tid & 7;        // read: 32 rows/pass, 8 float4 cols
    #pragma unroll
    for (int p = 0; p < 4; ++p) {
        int r = p * 32 + rr;
        float4 v = *(const float4*)&W[(size_t)(k0 + r) * N + n0 + cc * 4];
        tile[r][cc * 4 + 0] = v.x; tile[r][cc * 4 + 1] = v.y;
        tile[r][cc * 4 + 2] = v.z; tile[r][cc * 4 + 3] = v.w;
    }
    __syncthreads();
    const int nL = tid >> 3, kc = tid & 7;        // write: 32 n rows, 8 k-chunks
    #pragma unroll
    for (int q = 0; q < 2; ++q) {
        int kbase = kc * 8 + q * 64;
        ushort8_t o;
        #pragma unroll
        for (int j = 0; j < 8; ++j) o[j] = f2bf(tile[kbase + j][nL]);
        *(ushort8_t*)&Wt[(size_t)(n0 + nL) * K + k0 + kbase] = o;
    }
}

// ---------------------------------------------------------------- bf16 MFMA GEMM
// v3 schedule (T4 counted-vmcnt on the bt3/bt4 geometry):
// per K-step: ds_read frags(buf[cur]) -> lgkmcnt(0) -> barrier#1 ->
//             stage(t+2 -> buf[cur]) -> MFMA -> vmcnt(8|10) -> barrier#2.
// Tile t+1's loads get a FULL K-step to complete (issued at step t-1's phase 3,
// deadline at step t's end), and the end-of-step wait is counted (8/10 = the
// just-issued t+2 loads), never 0 in steady state.
// Race-safety: lgkmcnt(0)+barrier#1 = all waves done READING buf[cur] before
// t+2's async LDS writes can land there; per-wave vmcnt(N)+barrier#2 = ALL
// waves' t+1 loads landed before anyone reads buf[cur^1].
// LDS 64/80 KiB -> 2 blocks/CU preserved (inter-block overlap kept).
#define STG3_A(bufi, kt, r)                                                       \
    __builtin_amdgcn_global_load_lds(                                             \
        GLOBAL_AS(A + (size_t)(m0 + rRow[r]) * K + ((kt) << 6) + rOff[r]),        \
        LDS_AS(&As3[bufi][((r) * 256 + tid) * 8]), 16, 0, 0)
#define STG3_B(bufi, kt, r)                                                       \
    __builtin_amdgcn_global_load_lds(                                             \
        GLOBAL_AS(B + (size_t)(n0 + rRow[r]) * K + ((kt) << 6) + rOff[r]),        \
        LDS_AS(&Bs3[bufi][((r) * 256 + tid) * 8]), 16, 0, 0)

template <bool BF16_OUT>
__global__ __launch_bounds__(256, 2) void gemm_bt3_kernel(
        const unsigned short* __restrict__ A,
        const unsigned short* __restrict__ B,
        void* __restrict__ Cv, int M, int N, int K) {
    __shared__ __align__(16) unsigned short As3[2][128 * 64];   // 32 KiB
    __shared__ __align__(16) unsigned short Bs3[2][128 * 64];   // 32 KiB

    const int tid  = threadIdx.x;
    const int lane = tid & 63, wave = tid >> 6;
    const int wr = wave >> 1, wc = wave & 1;       // 2x2 wave grid, wave tile 64x64
    const int lrow = lane & 15, hi = lane >> 4;

    // XCD-aware bijective swizzle (both grids are multiples of 8)
    const int nwg = gridDim.x * gridDim.y;
    int wg = blockIdx.y * gridDim.x + blockIdx.x;
    wg = (wg & 7) * (nwg >> 3) + (wg >> 3);
    const int bx = wg % gridDim.x;
    const int by = wg / gridDim.x;
    const int m0 = by * 128, n0 = bx * 128;

    const int NT = K >> 6;

    // staging map: LDS linear (global_load_lds), source k pre-swizzled so logical
    // slot s of row r lives at physical slot (s ^ (r&7)). 8 lanes x 16B per row.
    int rRow[4], rOff[4];
    #pragma unroll
    for (int r = 0; r < 4; ++r) {
        int idx = r * 256 + tid;
        int row = idx >> 3;
        rRow[r] = row;
        rOff[r] = ((idx & 7) ^ (row & 7)) * 8;
    }

    // frag-read offsets (ushort units): row*64 + (slot ^ (row&7))*8
    const int sA0   = (hi ^ (lrow & 7)) * 8;       // kh toggles via ^32
    const int aBase = (wr * 64 + lrow) * 64;
    const int bBase = (wc * 64 + lrow) * 64;

    floatx4 acc[4][4] = {};

    // mode 0: stage t2 + counted vmcnt(8); mode 1: no stage, vmcnt(0); mode 2: final
    auto kstep = [&](int cur, int t2, int mode) {
        const unsigned short* ap = &As3[cur][0];
        const unsigned short* bp = &Bs3[cur][0];
        short8 af[4][2], bf[4][2];
        #pragma unroll
        for (int m = 0; m < 4; ++m)
            #pragma unroll
            for (int kh = 0; kh < 2; ++kh)
                af[m][kh] = *(const short8*)(ap + aBase + m * 1024 + (sA0 ^ (kh << 5)));
        #pragma unroll
        for (int n = 0; n < 4; ++n)
            #pragma unroll
            for (int kh = 0; kh < 2; ++kh)
                bf[n][kh] = *(const short8*)(bp + bBase + n * 1024 + (sA0 ^ (kh << 5)));
        // all our reads of buf[cur] complete before signaling barrier #1
        asm volatile("s_waitcnt lgkmcnt(0)" ::: "memory");
        __builtin_amdgcn_s_barrier();
        asm volatile("" ::: "memory");
        if (mode == 0) {
            #pragma unroll
            for (int r = 0; r < 4; ++r) STG3_A(cur, t2, r);
            #pragma unroll
            for (int r = 0; r < 4; ++r) STG3_B(cur, t2, r);
        }
        __builtin_amdgcn_s_setprio(1);
        #pragma unroll
        for (int m = 0; m < 4; ++m)
            #pragma unroll
            for (int n = 0; n < 4; ++n) {
                acc[m][n] = __builtin_amdgcn_mfma_f32_16x16x32_bf16(
                    af[m][0], bf[n][0], acc[m][n], 0, 0, 0);
                acc[m][n] = __builtin_amdgcn_mfma_f32_16x16x32_bf16(
                    af[m][1], bf[n][1], acc[m][n], 0, 0, 0);
            }
        __builtin_amdgcn_s_setprio(0);
        if (mode == 0) {
            asm volatile("s_waitcnt vmcnt(8)" ::: "memory");   // t+1 done; t+2 in flight
            __builtin_amdgcn_s_barrier();
            asm volatile("" ::: "memory");
        } else if (mode == 1) {
            asm volatile("s_waitcnt vmcnt(0)" ::: "memory");   // drain last tile
            __builtin_amdgcn_s_barrier();
            asm volatile("" ::: "memory");
        }
    };

    // prologue: stage tiles 0,1; wait for tile 0 (tile 1's 8 loads in flight)
    #pragma unroll
    for (int r = 0; r < 4; ++r) STG3_A(0, 0, r);
    #pragma unroll
    for (int r = 0; r < 4; ++r) STG3_B(0, 0, r);
    #pragma unroll
    for (int r = 0; r < 4; ++r) STG3_A(1, 1, r);
    #pragma unroll
    for (int r = 0; r < 4; ++r) STG3_B(1, 1, r);
    asm volatile("s_waitcnt vmcnt(8)" ::: "memory");
    S_BARRIER();

    int t = 0;
    for (; t < NT - 2; ++t) kstep(t & 1, t + 2, 0);
    kstep(t & 1, 0, 1); ++t;
    kstep(t & 1, 0, 2);

    const int rowb = hi * 4, col = lrow;
    #pragma unroll
    for (int mi = 0; mi < 4; ++mi)
        #pragma unroll
        for (int ni = 0; ni < 4; ++ni) {
            size_t base = (size_t)(m0 + wr * 64 + mi * 16 + rowb) * N
                        + (n0 + wc * 64 + ni * 16 + col);
            #pragma unroll
            for (int r = 0; r < 4; ++r) {
                if (BF16_OUT)
                    ((unsigned short*)Cv)[base + (size_t)r * N] = f2bf(acc[mi][ni][r]);
                else
                    ((float*)Cv)[base + (size_t)r * N] = acc[mi][ni][r];
            }
        }
}

// gemm_bt4: 128x192 tile for GEMM1, tail-free 512-block grid (R6: 111.8 µs,
// 922 TF, MfmaUtil 39.6%, FETCH 92 MB, 0 conflicts). v3 schedule as bt3,
// counted vmcnt(10) (4 A + 6 B loads per stage).
#define STG4_A(bufi, kt, r)                                                       \
    __builtin_amdgcn_global_load_lds(                                             \
        GLOBAL_AS(A + (size_t)(m0 + rRowA[r]) * K + ((kt) << 6) + rOffA[r]),      \
        LDS_AS(&As4[bufi][((r) * 256 + tid) * 8]), 16, 0, 0)
#define STG4_B(bufi, kt, r)                                                       \
    __builtin_amdgcn_global_load_lds(                                             \
        GLOBAL_AS(B + (size_t)(n0 + rRowB[r]) * K + ((kt) << 6) + rOffB[r]),      \
        LDS_AS(&Bs4[bufi][((r) * 256 + tid) * 8]), 16, 0, 0)

template <bool BF16_OUT>
__global__ __launch_bounds__(256, 2) void gemm_bt4_kernel(
        const unsigned short* __restrict__ A,
        const unsigned short* __restrict__ B,
        void* __restrict__ Cv, int M, int N, int K) {
    __shared__ __align__(16) unsigned short As4[2][128 * 64];   // 32 KiB
    __shared__ __align__(16) unsigned short Bs4[2][192 * 64];   // 48 KiB

    const int tid  = threadIdx.x;
    const int lane = tid & 63, wave = tid >> 6;
    const int wr = wave >> 1, wc = wave & 1;       // 2x2 wave grid, wave tile 64x96
    const int lrow = lane & 15, hi = lane >> 4;

    // XCD remap, then M-fastest tile order (gridDim.x = M-tiles)
    const int nwg = gridDim.x * gridDim.y;
    int wg = blockIdx.y * gridDim.x + blockIdx.x;
    wg = (wg & 7) * (nwg >> 3) + (wg >> 3);
    const int by = wg % gridDim.x;        // M-tile (fastest within XCD chunk)
    const int bx = wg / gridDim.x;        // N-tile
    const int m0 = by * 128, n0 = bx * 192;

    const int NT = K >> 6;

    // staging maps (source pre-swizzled: logical slot s of row r -> s ^ (r&7))
    int rRowA[4], rOffA[4];
    #pragma unroll
    for (int r = 0; r < 4; ++r) {
        int idx = r * 256 + tid;
        int row = idx >> 3;
        rRowA[r] = row;
        rOffA[r] = ((idx & 7) ^ (row & 7)) * 8;
    }
    int rRowB[6], rOffB[6];
    #pragma unroll
    for (int r = 0; r < 6; ++r) {
        int idx = r * 256 + tid;
        int row = idx >> 3;
        rRowB[r] = row;
        rOffB[r] = ((idx & 7) ^ (row & 7)) * 8;
    }

    const int sA0   = (hi ^ (lrow & 7)) * 8;       // kh toggles via ^32
    const int aBase = (wr * 64 + lrow) * 64;
    const int bBase = (wc * 96 + lrow) * 64;

    floatx4 acc[4][6] = {};

    auto kstep = [&](int cur, int t2, int mode) {
        const unsigned short* ap = &As4[cur][0];
        const unsigned short* bp = &Bs4[cur][0];
        short8 af[4][2], bf[6][2];
        #pragma unroll
        for (int m = 0; m < 4; ++m)
            #pragma unroll
            for (int kh = 0; kh < 2; ++kh)
                af[m][kh] = *(const short8*)(ap + aBase + m * 1024 + (sA0 ^ (kh << 5)));
        #pragma unroll
        for (int n = 0; n < 6; ++n)
            #pragma unroll
            for (int kh = 0; kh < 2; ++kh)
                bf[n][kh] = *(const short8*)(bp + bBase + n * 1024 + (sA0 ^ (kh << 5)));
        asm volatile("s_waitcnt lgkmcnt(0)" ::: "memory");
        __builtin_amdgcn_s_barrier();
        asm volatile("" ::: "memory");
        if (mode == 0) {
            #pragma unroll
            for (int r = 0; r < 4; ++r) STG4_A(cur, t2, r);
            #pragma unroll
            for (int r = 0; r < 6; ++r) STG4_B(cur, t2, r);
        }
        __builtin_amdgcn_s_setprio(1);
        #pragma unroll
        for (int m = 0; m < 4; ++m)
            #pragma unroll
            for (int n = 0; n < 6; ++n) {
                acc[m][n] = __builtin_amdgcn_mfma_f32_16x16x32_bf16(
                    af[m][0], bf[n][0], acc[m][n], 0, 0, 0);
                acc[m][n] = __builtin_amdgcn_mfma_f32_16x16x32_bf16(
                    af[m][1], bf[n][1], acc[m][n], 0, 0, 0);
            }
        __builtin_amdgcn_s_setprio(0);
        if (mode == 0) {
            asm volatile("s_waitcnt vmcnt(10)" ::: "memory");
            __builtin_amdgcn_s_barrier();
            asm volatile("" ::: "memory");
        } else if (mode == 1) {
            asm volatile("s_waitcnt vmcnt(0)" ::: "memory");
            __builtin_amdgcn_s_barrier();
            asm volatile("" ::: "memory");
        }
    };

    // prologue: stage tiles 0,1; wait for tile 0 (tile 1's 10 loads in flight)
    #pragma unroll
    for (int r = 0; r < 4; ++r) STG4_A(0, 0, r);
    #pragma unroll
    for (int r = 0; r < 6; ++r) STG4_B(0, 0, r);
    #pragma unroll
    for (int r = 0; r < 4; ++r) STG4_A(1, 1, r);
    #pragma unroll
    for (int r = 0; r < 6; ++r) STG4_B(1, 1, r);
    asm volatile("s_waitcnt vmcnt(10)" ::: "memory");
    S_BARRIER();

    int t = 0;
    for (; t < NT - 2; ++t) kstep(t & 1, t + 2, 0);
    kstep(t & 1, 0, 1); ++t;
    kstep(t & 1, 0, 2);

    const int rowb = hi * 4, col = lrow;
    #pragma unroll
    for (int mi = 0; mi < 4; ++mi)
        #pragma unroll
        for (int ni = 0; ni < 6; ++ni) {
            size_t base = (size_t)(m0 + wr * 64 + mi * 16 + rowb) * N
                        + (n0 + wc * 96 + ni * 16 + col);
            #pragma unroll
            for (int r = 0; r < 4; ++r) {
                if (BF16_OUT)
                    ((unsigned short*)Cv)[base + (size_t)r * N] = f2bf(acc[mi][ni][r]);
                else
                    ((float*)Cv)[base + (size_t)r * N] = acc[mi][ni][r];
            }
        }
}

// ------------------------------------- rope table: [t][i] -> (cos, sin), i in [0,64)
__global__ __launch_bounds__(256) void rope_table_kernel(
        const int* __restrict__ positions, float2* __restrict__ rope) {
    int idx = blockIdx.x * 256 + threadIdx.x;   // t*64 + i
    int t = idx >> 6, i = idx & 63;
    float inv_freq = expf((float)i * -0.2158673524681918f);   // -ln(1e6)/64
    float sn, cs;
    sincosf((float)positions[t] * inv_freq, &sn, &cs);
    rope[idx] = make_float2(cs, sn);
}

// ------------------------- qkv post: RMSNorm+RoPE (q,k) + V transpose, bf16 -> bf16
// grid (T/32, 48): heads 0-31 q, 32-39 k, 40-47 v. Block 256.
__global__ __launch_bounds__(256) void qkv_post_kernel(
        const unsigned short* __restrict__ qkv, const float2* __restrict__ rope,
        const float* __restrict__ qw, const float* __restrict__ kw,
        unsigned short* __restrict__ qb,        // [T][32][128]
        unsigned short* __restrict__ kb,        // [T][8][128]
        unsigned short* __restrict__ vbT) {     // [8][128][T]
    const int head = blockIdx.y;
    const int t0   = blockIdx.x * 32;
    const int tid  = threadIdx.x;

    if (head < 40) {
        const int r  = tid >> 3;       // token row 0..31
        const int q8 = tid & 7;        // 8 threads/row, 16 elems each
        const int t  = t0 + r;
        const unsigned short* src = qkv + (size_t)t * NQKV
                         + (head < 32 ? head * 128 : 4096 + (head - 32) * 128)
                         + q8 * 16;
        const float* w = (head < 32) ? qw : kw;

        ushort8_t u0 = *(const ushort8_t*)src;
        ushort8_t u1 = *(const ushort8_t*)(src + 8);
        float x[16];
        #pragma unroll
        for (int j = 0; j < 8; ++j) { x[j] = bf2f(u0[j]); x[8 + j] = bf2f(u1[j]); }

        float ss = 0.f;
        #pragma unroll
        for (int j = 0; j < 16; ++j) ss = fmaf(x[j], x[j], ss);
        ss += __shfl_xor(ss, 1); ss += __shfl_xor(ss, 2); ss += __shfl_xor(ss, 4);
        float sc = rsqrtf(ss * (1.f / 128.f) + 1e-5f);

        float xn[16], xp[16];
        #pragma unroll
        for (int j = 0; j < 16; ++j) xn[j] = x[j] * sc * w[q8 * 16 + j];
        #pragma unroll
        for (int j = 0; j < 16; ++j) xp[j] = __shfl_xor(xn[j], 4);

        const float2* rp = rope + (size_t)t * 64 + (q8 & 3) * 16;
        ushort8_t o0, o1;
        #pragma unroll
        for (int j = 0; j < 8; ++j) {
            float2 cs = rp[j];
            float res = (q8 < 4) ? (xn[j] * cs.x - xp[j] * cs.y)
                                 : (xn[j] * cs.x + xp[j] * cs.y);
            o0[j] = f2bf(res);
        }
        #pragma unroll
        for (int j = 0; j < 8; ++j) {
            float2 cs = rp[8 + j];
            float res = (q8 < 4) ? (xn[8+j] * cs.x - xp[8+j] * cs.y)
                                 : (xn[8+j] * cs.x + xp[8+j] * cs.y);
            o1[j] = f2bf(res);
        }
        unsigned short* dst = (head < 32)
            ? qb + ((size_t)t * 32 + head) * 128 + q8 * 16
            : kb + ((size_t)t * 8 + (head - 32)) * 128 + q8 * 16;
        *(ushort8_t*)dst       = o0;
        *(ushort8_t*)(dst + 8) = o1;
    } else {
        __shared__ float tile[128][33];
        const int hk = head - 40;
        {
            const int r = tid >> 3, c8 = tid & 7;
            const unsigned short* src =
                qkv + (size_t)(t0 + r) * NQKV + 5120 + hk * 128 + c8 * 16;
            ushort8_t u0 = *(const ushort8_t*)src;
            ushort8_t u1 = *(const ushort8_t*)(src + 8);
            #pragma unroll
            for (int j = 0; j < 8; ++j) {
                tile[c8 * 16 + j][r]     = bf2f(u0[j]);
                tile[c8 * 16 + 8 + j][r] = bf2f(u1[j]);
            }
        }
        __syncthreads();
        {
            const int d = tid >> 1, th = tid & 1;
            ushort8_t o0, o1;
            #pragma unroll
            for (int j = 0; j < 8; ++j) o0[j] = f2bf(tile[d][th * 16 + j]);
            #pragma unroll
            for (int j = 0; j < 8; ++j) o1[j] = f2bf(tile[d][th * 16 + 8 + j]);
            unsigned short* dst = vbT + ((size_t)hk * 128 + d) * T_SEQ + t0 + th * 16;
            *(ushort8_t*)dst       = o0;
            *(ushort8_t*)(dst + 8) = o1;
        }
    }
}

// ------------------- MFMA sliding-window flash attention, fixed-shift softmax
// p = exp(score - SHIFT) is safe: |score| <= 11.32 provably (see SHIFT above).
// No running max / rescale; l accumulated per-lane, reduced once in epilogue.
// v2: double-buffered K/V staging (neutral vs serial in R9 — kept, TLP at
// 4 blocks/CU already hides staging latency).
__global__ __launch_bounds__(256) void attention_kernel(
        const unsigned short* __restrict__ qb,
        const unsigned short* __restrict__ kb,
        const unsigned short* __restrict__ vbT,
        unsigned short* __restrict__ attnb) {
    const int h    = blockIdx.x & 31;
    const int Q0   = (blockIdx.x >> 5) * 64;
    const int tid  = threadIdx.x, wave = tid >> 6, lane = tid & 63;
    const int keyA = lane & 15, g = lane >> 4;
    const int hk   = h >> 2;
    const int qlo  = Q0 + wave * 16;

    __shared__ __align__(16) unsigned short ks [2][32 * 128];   // [key][d]
    __shared__ __align__(16) unsigned short vsT[2][128 * 32];   // [d][key]
    __shared__ __align__(16) unsigned short Pa [4 * 16 * 40];   // per-wave 16x32 (+8 pad)

    unsigned short* pw = Pa + wave * 640;

    // per-thread staging addresses (c = i*256+tid for i in {0,1})
    int kRow[2], kOff[2], vD[2], vOff[2];
    #pragma unroll
    for (int i = 0; i < 2; ++i) {
        int c = i * 256 + tid;
        {   int row = c >> 4, u = c & 15;
            kRow[i] = row; kOff[i] = (u ^ (row & 7)) * 8; }
        {   int d = c >> 2, u = c & 3;
            vD[i] = d; vOff[i] = (u ^ (d & 3)) * 8; }
    }

    auto stage = [&](int buf, int s0) {
        #pragma unroll
        for (int i = 0; i < 2; ++i) {
            int c = i * 256 + tid;
            const unsigned short* kp =
                kb + ((size_t)(s0 + kRow[i]) * 8 + hk) * 128 + kOff[i];
            __builtin_amdgcn_global_load_lds(GLOBAL_AS(kp),
                LDS_AS(&ks[buf][c * 8]), 16, 0, 0);
            const unsigned short* vp =
                vbT + ((size_t)hk * 128 + vD[i]) * T_SEQ + s0 + vOff[i];
            __builtin_amdgcn_global_load_lds(GLOBAL_AS(vp),
                LDS_AS(&vsT[buf][c * 8]), 16, 0, 0);
        }
    };

    short8 qa[4];
    {
        const unsigned short* qp = qb + ((size_t)(qlo + keyA) * 32 + h) * 128 + g * 8;
        #pragma unroll
        for (int s = 0; s < 4; ++s) qa[s] = *(const short8*)(qp + s * 32);
    }

    floatx4 acc[8] = {};
    float l_part[4] = {0.f, 0.f, 0.f, 0.f};

    const int s_begin = (Q0 >= WINDOW) ? ((Q0 - (WINDOW - 1)) & ~31) : 0;
    const int s_end   = Q0 + 63;

    // prologue: stage first tile
    stage(0, s_begin);
    asm volatile("s_waitcnt vmcnt(0)" ::: "memory");
    S_BARRIER();

    int cur = 0;
    for (int s0 = s_begin; s0 <= s_end; s0 += 32) {
        if (s0 + 32 <= s_end) stage(cur ^ 1, s0 + 32);   // prefetch next tile

        if (s0 <= qlo + 15 && s0 + 31 >= qlo - (WINDOW - 1)) {
            const unsigned short* ksb  = &ks[cur][0];
            const unsigned short* vsb  = &vsT[cur][0];
            floatx4 sa0 = {}, sa1 = {};
            #pragma unroll
            for (int kst = 0; kst < 4; ++kst) {
                int u = g + 4 * kst;
                short8 k0 = *(const short8*)(ksb + keyA * 128 + (u ^ (keyA & 7)) * 8);
                short8 k1 = *(const short8*)(ksb + (16 + keyA) * 128 + (u ^ ((16 + keyA) & 7)) * 8);
                sa0 = __builtin_amdgcn_mfma_f32_16x16x32_bf16(qa[kst], k0, sa0, 0, 0, 0);
                sa1 = __builtin_amdgcn_mfma_f32_16x16x32_bf16(qa[kst], k1, sa1, 0, 0, 0);
            }
            float p0[4], p1[4];
            #pragma unroll
            for (int r = 0; r < 4; ++r) {
                int row = qlo + 4 * g + r;
                int sA = s0 + keyA, sB = sA + 16;
                bool vA = (sA <= row) && (row - sA < WINDOW);
                bool vB = (sB <= row) && (row - sB < WINDOW);
                p0[r] = vA ? __expf(fmaf(sa0[r], SCALE, -SHIFT)) : 0.f;
                p1[r] = vB ? __expf(fmaf(sa1[r], SCALE, -SHIFT)) : 0.f;
                l_part[r] += p0[r] + p1[r];
            }
            #pragma unroll
            for (int r = 0; r < 4; ++r) {
                pw[(4 * g + r) * 40 + keyA]      = f2bf(p0[r]);
                pw[(4 * g + r) * 40 + keyA + 16] = f2bf(p1[r]);
            }
            short8 pf = *(const short8*)(pw + keyA * 40 + g * 8);

            #pragma unroll
            for (int t = 0; t < 8; ++t) {
                int d = t * 16 + keyA;
                short8 vf = *(const short8*)(vsb + d * 32 + (g ^ (d & 3)) * 8);
                acc[t] = __builtin_amdgcn_mfma_f32_16x16x32_bf16(pf, vf, acc[t], 0, 0, 0);
            }
        }
        asm volatile("s_waitcnt vmcnt(0)" ::: "memory");
        S_BARRIER();
        cur ^= 1;
    }

    float inv[4];
    #pragma unroll
    for (int r = 0; r < 4; ++r) {
        float l = l_part[r];
        l += __shfl_xor(l, 1); l += __shfl_xor(l, 2);
        l += __shfl_xor(l, 4); l += __shfl_xor(l, 8);
        inv[r] = 1.f / l;
    }
    #pragma unroll
    for (int t = 0; t < 8; ++t)
        #pragma unroll
        for (int r = 0; r < 4; ++r)
            attnb[(size_t)(qlo + 4 * g + r) * 4096 + h * 128 + t * 16 + keyA] =
                f2bf(acc[t][r] * inv[r]);
}

// ----------------------------------------------------------------------- launcher
extern "C" void kernel_launch(void* const* d_in, const int* in_sizes, int n_in,
                              void* d_out, int out_size, void* d_ws, size_t ws_size,
                              hipStream_t stream) {
    const int*   positions = (const int*)  d_in[0];
    const float* hs        = (const float*)d_in[1];
    const float* w_qkv     = (const float*)d_in[2];
    const float* q_norm_w  = (const float*)d_in[3];
    const float* k_norm_w  = (const float*)d_in[4];
    const float* w_o       = (const float*)d_in[5];
    float* out = (float*)d_out;

    char* ws = (char*)d_ws;
    // layout (121 MB):
    //   [0,16M)    hs bf16     (dead after gemm1; reused as attnb bf16)
    //   [16M,64M)  w_qkv^T bf16 (dead after gemm1; then qb/kb/vbT/rope live here)
    //     [16M,32M) qb bf16 [T][32][128]
    //     [32M,36M) kb bf16 [T][8][128]
    //     [36M,40M) vbT bf16 [8][128][T]
    //     [40M,41M) rope float2 [T][64]
    //   [64M,96M)  w_o^T bf16
    //   [96M,120M) qkv bf16 [T][6144]
    unsigned short* hsb   = (unsigned short*)(ws);
    unsigned short* wqkvt = (unsigned short*)(ws + (size_t)(16u << 20));
    unsigned short* wot   = (unsigned short*)(ws + (size_t)(64u << 20));
    unsigned short* qkvb  = (unsigned short*)(ws + (size_t)(96u << 20));
    unsigned short* qb    = (unsigned short*)(ws + (size_t)(16u << 20));
    unsigned short* kb    = (unsigned short*)(ws + (size_t)(32u << 20));
    unsigned short* vbT   = (unsigned short*)(ws + (size_t)(36u << 20));
    float2*         rope  = (float2*)        (ws + (size_t)(40u << 20));
    unsigned short* attnb = hsb;   // alias: hs-bf16 dead after gemm1

    convert_bf16_kernel<<<dim3((T_SEQ * HIDDEN / 4 + 255) / 256), 256, 0, stream>>>(
        hs, hsb, T_SEQ * HIDDEN / 4);
    transpose_bf16_kernel<<<dim3(NQKV / 32, HIDDEN / 128), 256, 0, stream>>>(
        w_qkv, wqkvt, HIDDEN, NQKV);
    transpose_bf16_kernel<<<dim3(HIDDEN / 32, HIDDEN / 128), 256, 0, stream>>>(
        w_o, wot, HIDDEN, HIDDEN);
    gemm_bt4_kernel<true><<<dim3(T_SEQ / 128, NQKV / 192), 256, 0, stream>>>(
        hsb, wqkvt, qkvb, T_SEQ, NQKV, HIDDEN);
    rope_table_kernel<<<dim3(T_SEQ * 64 / 256), 256, 0, stream>>>(positions, rope);
    qkv_post_kernel<<<dim3(T_SEQ / 32, 48), 256, 0, stream>>>(
        qkvb, rope, q_norm_w, k_norm_w, qb, kb, vbT);
    attention_kernel<<<dim3((T_SEQ / 64) * NHEAD), 256, 0, stream>>>(
        qb, kb, vbT, attnb);
    gemm_bt3_kernel<false><<<dim3(HIDDEN / 128, T_SEQ / 128), 256, 0, stream>>>(
        attnb, wot, out, T_SEQ, HIDDEN, HIDDEN);
}